// Round 4
// baseline (303.634 us; speedup 1.0000x reference)
//
#include <hip/hip_runtime.h>
#include <math.h>

constexpr int B = 4;
constexpr int N = 8192;
constexpr int KNN = 8;
constexpr int SLICES = 8;      // candidate slices == waves per block
constexpr int QPB = 64;        // queries per block (one per lane)
constexpr int L = N / SLICES;  // 1024 candidates per slice

// Prologue: pack pred = src+flow and target as float4 (x, y, z, |p|^2/2).
// Also zeroes the output accumulator (harness poisons it before each call).
__global__ __launch_bounds__(256) void prep_kernel(
    const float* __restrict__ src, const float* __restrict__ tgt,
    const float* __restrict__ flow, float4* __restrict__ pred4,
    float4* __restrict__ tgt4, float* __restrict__ out) {
  int i = blockIdx.x * 256 + threadIdx.x;
  if (i == 0) out[0] = 0.0f;
  if (i >= B * N) return;
  float px = src[3 * i + 0] + flow[3 * i + 0];
  float py = src[3 * i + 1] + flow[3 * i + 1];
  float pz = src[3 * i + 2] + flow[3 * i + 2];
  pred4[i] = make_float4(px, py, pz, 0.5f * (px * px + py * py + pz * pz));
  float tx = tgt[3 * i + 0];
  float ty = tgt[3 * i + 1];
  float tz = tgt[3 * i + 2];
  tgt4[i] = make_float4(tx, ty, tz, 0.5f * (tx * tx + ty * ty + tz * tz));
}

// Insert tv into sorted ascending d[0..7], keeping the smallest 8 sorted.
// Exact identity: d'[0] = min(d0,tv); d'[i] = med3(d[i-1], d[i], tv).
// 8 independent ops (depth 1), no temporaries beyond nd[].
__device__ __forceinline__ void insert8(float (&d)[KNN], float tv) {
  float n0 = fminf(d[0], tv);
  float n1 = __builtin_amdgcn_fmed3f(d[0], d[1], tv);
  float n2 = __builtin_amdgcn_fmed3f(d[1], d[2], tv);
  float n3 = __builtin_amdgcn_fmed3f(d[2], d[3], tv);
  float n4 = __builtin_amdgcn_fmed3f(d[3], d[4], tv);
  float n5 = __builtin_amdgcn_fmed3f(d[4], d[5], tv);
  float n6 = __builtin_amdgcn_fmed3f(d[5], d[6], tv);
  float n7 = __builtin_amdgcn_fmed3f(d[6], d[7], tv);
  d[0] = n0; d[1] = n1; d[2] = n2; d[3] = n3;
  d[4] = n4; d[5] = n5; d[6] = n6; d[7] = n7;
}

// Block = 8 waves of 64 lanes. Wave w streams candidate slice w (1024 cands)
// for 64 queries (one per lane). Top-8 per lane maintained branchlessly via
// med3 sorted insertion: 3 FMA + 1 min + 7 med3 = 11 VALU per candidate,
// live set ~20 VGPRs so the 8-load batches can stay fully in flight.
__global__ __launch_bounds__(512, 4) void chamfer_kernel(
    const float4* __restrict__ pred4, const float4* __restrict__ tgt4,
    float* __restrict__ out) {
  int blk = blockIdx.x;           // 1024 blocks
  int dir = blk >> 9;             // 0: pred->tgt, 1: tgt->pred
  int batch = (blk >> 7) & 3;     // 4 batches
  int chunk = blk & 127;          // 128 chunks of 64 queries
  const float4* __restrict__ qarr = (dir == 0 ? pred4 : tgt4) + batch * N;
  const float4* __restrict__ parr = (dir == 0 ? tgt4 : pred4) + batch * N;

  int lane = threadIdx.x & 63;
  int wave = threadIdx.x >> 6;

  float4 q = qarr[chunk * QPB + lane];
  float nqx = -q.x, nqy = -q.y, nqz = -q.z;
  const float4* __restrict__ p0 = parr + wave * L;

  float d[KNN];
#pragma unroll
  for (int i = 0; i < KNN; ++i) d[i] = INFINITY;

  for (int j = 0; j < L; j += 8) {
    float4 p[8];
#pragma unroll
    for (int u = 0; u < 8; ++u) p[u] = p0[j + u];  // 8 loads in flight
#pragma unroll
    for (int u = 0; u < 8; ++u) {
      float tv = __builtin_fmaf(nqx, p[u].x,
                 __builtin_fmaf(nqy, p[u].y,
                 __builtin_fmaf(nqz, p[u].z, p[u].w)));
      insert8(d, tv);
    }
  }

  // merge 8 slices' sorted top-8 per query through LDS (stride 9, <=2-way)
  __shared__ float part[SLICES][QPB][KNN + 1];
#pragma unroll
  for (int i = 0; i < KNN; ++i) part[wave][lane][i] = d[i];
  __syncthreads();

  if (wave == 0) {
    float m[KNN];
#pragma unroll
    for (int i = 0; i < KNN; ++i) m[i] = part[0][lane][i];  // already sorted
    for (int s = 1; s < SLICES; ++s) {
#pragma unroll
      for (int i = 0; i < KNN; ++i) insert8(m, part[s][lane][i]);
    }
    float q2 = 2.0f * q.w;
    float s_ = 0.0f;
#pragma unroll
    for (int i = 0; i < KNN; ++i) {
      float d2 = fmaxf(__builtin_fmaf(2.0f, m[i], q2), 0.0f);
      s_ += sqrtf(d2);
    }
    float val = s_ * (1.0f / KNN);
    for (int off = 32; off; off >>= 1) val += __shfl_down(val, off, 64);
    if (lane == 0) atomicAdd(out, val * (1.0f / (B * N)));
  }
}

extern "C" void kernel_launch(void* const* d_in, const int* in_sizes, int n_in,
                              void* d_out, int out_size, void* d_ws, size_t ws_size,
                              hipStream_t stream) {
  const float* src = (const float*)d_in[0];
  const float* tgt = (const float*)d_in[1];
  const float* flow = (const float*)d_in[2];
  float* out = (float*)d_out;
  float4* pred4 = (float4*)d_ws;
  float4* tgt4 = pred4 + B * N;

  prep_kernel<<<(B * N) / 256, 256, 0, stream>>>(src, tgt, flow, pred4, tgt4, out);
  chamfer_kernel<<<2 * B * (N / QPB), 512, 0, stream>>>(pred4, tgt4, out);
}

// Round 5
// 200.859 us; speedup vs baseline: 1.5117x; 1.5117x over previous
//
#include <hip/hip_runtime.h>
#include <math.h>

constexpr int B = 4;
constexpr int N = 8192;
constexpr int KNN = 8;
constexpr int SLICES = 8;      // candidate slices == waves per block
constexpr int QPB = 64;        // queries per wave (one per lane)
constexpr int L = N / SLICES;  // 1024 candidates per slice
constexpr int CHUNK = 64;      // candidates staged per LDS chunk
constexpr int NCHUNK = L / CHUNK;

// Prologue: pack pred = src+flow and target as float4 (x, y, z, |p|^2/2).
// Also zeroes the output accumulator (harness poisons it before each call).
__global__ __launch_bounds__(256) void prep_kernel(
    const float* __restrict__ src, const float* __restrict__ tgt,
    const float* __restrict__ flow, float4* __restrict__ pred4,
    float4* __restrict__ tgt4, float* __restrict__ out) {
  int i = blockIdx.x * 256 + threadIdx.x;
  if (i == 0) out[0] = 0.0f;
  if (i >= B * N) return;
  float px = src[3 * i + 0] + flow[3 * i + 0];
  float py = src[3 * i + 1] + flow[3 * i + 1];
  float pz = src[3 * i + 2] + flow[3 * i + 2];
  pred4[i] = make_float4(px, py, pz, 0.5f * (px * px + py * py + pz * pz));
  float tx = tgt[3 * i + 0];
  float ty = tgt[3 * i + 1];
  float tz = tgt[3 * i + 2];
  tgt4[i] = make_float4(tx, ty, tz, 0.5f * (tx * tx + ty * ty + tz * tz));
}

// Insert tv into sorted ascending d[0..7], keeping the smallest 8 sorted.
// Exact identity: d'[0] = min(d0,tv); d'[i] = med3(d[i-1], d[i], tv).
// 8 independent ops (depth 1).
__device__ __forceinline__ void insert8(float (&d)[KNN], float tv) {
  float n0 = fminf(d[0], tv);
  float n1 = __builtin_amdgcn_fmed3f(d[0], d[1], tv);
  float n2 = __builtin_amdgcn_fmed3f(d[1], d[2], tv);
  float n3 = __builtin_amdgcn_fmed3f(d[2], d[3], tv);
  float n4 = __builtin_amdgcn_fmed3f(d[3], d[4], tv);
  float n5 = __builtin_amdgcn_fmed3f(d[4], d[5], tv);
  float n6 = __builtin_amdgcn_fmed3f(d[5], d[6], tv);
  float n7 = __builtin_amdgcn_fmed3f(d[6], d[7], tv);
  d[0] = n0; d[1] = n1; d[2] = n2; d[3] = n3;
  d[4] = n4; d[5] = n5; d[6] = n6; d[7] = n7;
}

// Block = 8 waves of 64 lanes; wave w scans candidate slice w for its 64
// queries (one per lane). Candidates are staged per-wave into double-buffered
// LDS (coalesced global_load_dwordx4 + ds_write_b128, prefetched one chunk
// ahead), then broadcast-read with ds_read_b128 — all inner-loop operands are
// VGPRs: 1 ds_read + 3 fma + 1 min + 7 med3 = 12 VALU inst per candidate.
__global__ __launch_bounds__(512, 8) void chamfer_kernel(
    const float4* __restrict__ pred4, const float4* __restrict__ tgt4,
    float* __restrict__ out) {
  int blk = blockIdx.x;           // 1024 blocks
  int dir = blk >> 9;             // 0: pred->tgt, 1: tgt->pred
  int batch = (blk >> 7) & 3;     // 4 batches
  int chunk = blk & 127;          // 128 chunks of 64 queries
  const float4* __restrict__ qarr = (dir == 0 ? pred4 : tgt4) + batch * N;
  const float4* __restrict__ parr = (dir == 0 ? tgt4 : pred4) + batch * N;

  int lane = threadIdx.x & 63;
  int wave = threadIdx.x >> 6;

  float4 q = qarr[chunk * QPB + lane];
  float nqx = -q.x, nqy = -q.y, nqz = -q.z;
  const float4* __restrict__ p0 = parr + wave * L;

  __shared__ float4 stage[SLICES][2][CHUNK];   // 16 KB, per-wave dbuf
  __shared__ float part[SLICES][QPB][KNN + 1]; // 18 KB, slice merge

  float d[KNN];
#pragma unroll
  for (int i = 0; i < KNN; ++i) d[i] = INFINITY;

  float4 my = p0[lane];  // prefetch chunk 0 (coalesced, 1 KB per wave)

  for (int c = 0; c < NCHUNK; ++c) {
    int cur = c & 1;
    stage[wave][cur][lane] = my;               // ds_write_b128
    if (c + 1 < NCHUNK) my = p0[(c + 1) * CHUNK + lane];  // global prefetch
#pragma unroll 8
    for (int i = 0; i < CHUNK; ++i) {
      float4 p = stage[wave][cur][i];          // broadcast ds_read_b128
      float tv = __builtin_fmaf(nqx, p.x,
                 __builtin_fmaf(nqy, p.y,
                 __builtin_fmaf(nqz, p.z, p.w)));
      insert8(d, tv);
    }
  }

  // merge 8 slices' sorted top-8 per query through LDS (stride 9)
#pragma unroll
  for (int i = 0; i < KNN; ++i) part[wave][lane][i] = d[i];
  __syncthreads();

  if (wave == 0) {
    float m[KNN];
#pragma unroll
    for (int i = 0; i < KNN; ++i) m[i] = part[0][lane][i];  // already sorted
    for (int s = 1; s < SLICES; ++s) {
#pragma unroll
      for (int i = 0; i < KNN; ++i) insert8(m, part[s][lane][i]);
    }
    float q2 = 2.0f * q.w;
    float s_ = 0.0f;
#pragma unroll
    for (int i = 0; i < KNN; ++i) {
      float d2 = fmaxf(__builtin_fmaf(2.0f, m[i], q2), 0.0f);
      s_ += sqrtf(d2);
    }
    float val = s_ * (1.0f / KNN);
    for (int off = 32; off; off >>= 1) val += __shfl_down(val, off, 64);
    if (lane == 0) atomicAdd(out, val * (1.0f / (B * N)));
  }
}

extern "C" void kernel_launch(void* const* d_in, const int* in_sizes, int n_in,
                              void* d_out, int out_size, void* d_ws, size_t ws_size,
                              hipStream_t stream) {
  const float* src = (const float*)d_in[0];
  const float* tgt = (const float*)d_in[1];
  const float* flow = (const float*)d_in[2];
  float* out = (float*)d_out;
  float4* pred4 = (float4*)d_ws;
  float4* tgt4 = pred4 + B * N;

  prep_kernel<<<(B * N) / 256, 256, 0, stream>>>(src, tgt, flow, pred4, tgt4, out);
  chamfer_kernel<<<2 * B * (N / QPB), 512, 0, stream>>>(pred4, tgt4, out);
}